// Round 6
// baseline (16512.126 us; speedup 1.0000x reference)
//
#include <hip/hip_runtime.h>
#include <hip/hip_bf16.h>

typedef __bf16 bf16x8 __attribute__((ext_vector_type(8)));
typedef float f32x4 __attribute__((ext_vector_type(4)));

#define MFMA16(a, b, c) __builtin_amdgcn_mfma_f32_16x16x32_bf16((a), (b), (c), 0, 0, 0)

#define BB 64
#define TT 256
#define II 512
#define SS 256
#define DD 1024
#define HH 1024

// ---- ws layout (bytes); total ~42.6 MB (<= 43.02 MB proven round 4) --------
#define OFF_A ((size_t)0)            // 32MB bf16 activation slot (a0, then a2)
#define OFF_Z ((size_t)33554432)     // 8MB bf16 z archive (T,B,S)
#define OFF_H32 ((size_t)41943040)   // f32 [2][64][1024] shared h carry (sc1 access)
#define OFF_Z32 ((size_t)42467328)   // f32 [64][256] shared z carry (sc1 access)
#define OFF_CNT ((size_t)42532864)   // int hcnt[256] | zcnt[256]

// ---- d_out (fp32, 66,977,792 B) scratch layout -----------------------------
// [0,32MB): h_all bf16 rows (t*64+b)*1024  (dead after dec0 -> a1 bf16)
// [34MB,42MB): xm bf16 (T,B,S)  [42MB,50MB): xv bf16 (T,B,S)  (dead after scan)
#define DO_XM ((size_t)35651584)
#define DO_XV ((size_t)44040192)
#define OUTD_ELEMS 8355840  // 64*255*512

__device__ __forceinline__ float fsig(float x) { return 1.f / (1.f + __expf(-x)); }
__device__ __forceinline__ float ftanh(float x) {
  float ax = __builtin_fabsf(x);
  float e = __expf(-2.f * ax);
  float r = (1.f - e) / (1.f + e);
  return __builtin_copysignf(r, x);
}

// 8 fp32 (cached load) -> bf16x8
__device__ __forceinline__ bf16x8 ld8f(const float* p) {
  float4 a = *(const float4*)p;
  float4 b = *(const float4*)(p + 4);
  bf16x8 r;
  r[0] = (__bf16)a.x; r[1] = (__bf16)a.y; r[2] = (__bf16)a.z; r[3] = (__bf16)a.w;
  r[4] = (__bf16)b.x; r[5] = (__bf16)b.y; r[6] = (__bf16)b.z; r[7] = (__bf16)b.w;
  return r;
}

// ---- coherence-bypassing data path (relaxed agent atomics -> sc1 ops) ------
#define A_LD(p) __hip_atomic_load((p), __ATOMIC_RELAXED, __HIP_MEMORY_SCOPE_AGENT)
#define A_ST(p, v) __hip_atomic_store((p), (v), __ATOMIC_RELAXED, __HIP_MEMORY_SCOPE_AGENT)

__device__ __forceinline__ float ld_coh(const unsigned* p) {
  return __uint_as_float(A_LD(p));
}
__device__ __forceinline__ void st_coh(unsigned* p, float v) { A_ST(p, __float_as_uint(v)); }

// 8 fp32 via coherent dword loads -> bf16x8 (pipelined by compiler)
__device__ __forceinline__ bf16x8 ld8a(const unsigned* p) {
  unsigned u[8];
#pragma unroll
  for (int i = 0; i < 8; ++i) u[i] = A_LD(p + i);
  bf16x8 r;
#pragma unroll
  for (int i = 0; i < 8; ++i) r[i] = (__bf16)__uint_as_float(u[i]);
  return r;
}

// ---- sync: relaxed signal after vmcnt drain; relaxed poll (no cache maint) -
__device__ __forceinline__ void signal_inc(int* p) {
  asm volatile("s_waitcnt vmcnt(0)" ::: "memory");  // sc1 stores now at coherence point
  __syncthreads();
  if (threadIdx.x == 0)
    __hip_atomic_fetch_add(p, 1, __ATOMIC_RELAXED, __HIP_MEMORY_SCOPE_AGENT);
}
__device__ __forceinline__ void waitcnt_ge(int* p, int target) {
  if (threadIdx.x == 0) {
    while (__hip_atomic_load(p, __ATOMIC_RELAXED, __HIP_MEMORY_SCOPE_AGENT) < target)
      __builtin_amdgcn_s_sleep(1);
  }
  __syncthreads();
}

// ---------------------------------------------------------------------------
// k_xmv: xm/xv = x @ Wm[:, :I].T, x @ Wv[:, :I].T -> bf16 into d_out scratch.
// Also zeroes the scan counters. m = t*64+b (16384 rows), n = 512, K = 512.
// ---------------------------------------------------------------------------
__global__ __launch_bounds__(256) void k_xmv(const float* __restrict__ x,
                                             const float* __restrict__ Wm,
                                             const float* __restrict__ Wv,
                                             char* __restrict__ doutc, char* __restrict__ ws) {
  if (blockIdx.x == 0 && blockIdx.y == 0) {
    int* cnt = (int*)(ws + OFF_CNT);
    cnt[threadIdx.x] = 0;
    cnt[threadIdx.x + 256] = 0;
  }
  __bf16* xm = (__bf16*)(doutc + DO_XM);
  __bf16* xv = (__bf16*)(doutc + DO_XV);

  int m0 = blockIdx.x * 64, n0 = blockIdx.y * 64;
  int tid = threadIdx.x, lane = tid & 63, wv = tid >> 6;
  int n15 = lane & 15, q8 = (lane >> 4) * 8;

  int row = m0 + wv * 16 + n15;  // m = t*64 + b
  int t = row >> 6, b = row & 63;
  const float* arow = x + ((size_t)(b * TT + t)) * II + q8;

  const float* brow[4];
#pragma unroll
  for (int j = 0; j < 4; ++j) {
    int c = n0 + j * 16 + n15;
    brow[j] = ((c < SS) ? (Wm + (size_t)c * (II + DD)) : (Wv + (size_t)(c - SS) * (II + DD))) + q8;
  }
  f32x4 acc[4] = {};
#pragma unroll 4
  for (int k = 0; k < II; k += 32) {
    bf16x8 a = ld8f(arow + k);
#pragma unroll
    for (int j = 0; j < 4; ++j) acc[j] = MFMA16(a, ld8f(brow[j] + k), acc[j]);
  }
  int mb = m0 + wv * 16 + (lane >> 4) * 4;
#pragma unroll
  for (int j = 0; j < 4; ++j) {
    int c = n0 + j * 16 + n15;
    __bf16* dst = (c < SS) ? (xm + c) : (xv + (c - SS));
#pragma unroll
    for (int r = 0; r < 4; ++r) dst[(size_t)(mb + r) * SS] = (__bf16)acc[j][r];
  }
}

// ---------------------------------------------------------------------------
// k_scan: persistent. Blocks 0..63 = GRU (16 h-cols each; W_ih + n-gate W_hh
// in LDS bf16; r/z-gate W_hh streamed from L2-resident global — no cache
// invalidates anywhere, so they STAY resident). Blocks 64..79 = posterior.
// Carry h/z cross XCDs via sc1 (relaxed-atomic) dword loads/stores.
// ---------------------------------------------------------------------------
__global__ __launch_bounds__(256, 1) void k_scan(
    const float* __restrict__ Wih, const float* __restrict__ Whh,
    const float* __restrict__ bih, const float* __restrict__ bhh,
    const float* __restrict__ Wm, const float* __restrict__ bm,
    const float* __restrict__ Wv, const float* __restrict__ bv,
    const float* __restrict__ noise, char* __restrict__ ws, char* __restrict__ doutc) {
  // LDS: [0,12288) W_ih frag-packed [g][kk<8][lane][8]; [12288,28672) W_hh n-gate
  __shared__ __bf16 wl[28672];

  unsigned* h32[2] = {(unsigned*)(ws + OFF_H32), (unsigned*)(ws + OFF_H32) + (size_t)BB * DD};
  unsigned* z32 = (unsigned*)(ws + OFF_Z32);
  __bf16* z_all = (__bf16*)(ws + OFF_Z);
  __bf16* h_all = (__bf16*)doutc;
  const __bf16* xm = (const __bf16*)(doutc + DO_XM);
  const __bf16* xv = (const __bf16*)(doutc + DO_XV);
  int* hcnt = (int*)(ws + OFF_CNT);
  int* zcnt = hcnt + 256;

  int blk = blockIdx.x, tid = threadIdx.x, lane = tid & 63, wv = tid >> 6;
  int n15 = lane & 15, q8 = (lane >> 4) * 8, q4 = (lane >> 4) * 4;
  const int rb = wv * 16 + n15;  // A-fragment batch row

  if (blk < 64) {
    int c0 = blk * 16, cc = c0 + n15;
    // ---- stage W_ih (all gates) + W_hh n-gate into LDS, bf16 frag-packed
    for (int v = tid; v < 1536; v += 256) {
      int lp = v & 63, kk = (v >> 6) & 7, g = v >> 9;
      int col = c0 + (lp & 15), ks = kk * 32 + (lp >> 4) * 8;
      *(bf16x8*)(wl + (size_t)v * 8) = ld8f(Wih + (size_t)(g * DD + col) * SS + ks);
    }
    for (int v = tid; v < 2048; v += 256) {
      int lp = v & 63, kk = v >> 6;
      int col = c0 + (lp & 15), ks = kk * 32 + (lp >> 4) * 8;
      *(bf16x8*)(wl + 12288 + (size_t)v * 8) = ld8f(Whh + (size_t)(2 * DD + col) * DD + ks);
    }
    __syncthreads();

    float brs = bih[cc] + bhh[cc];
    float bzs = bih[DD + cc] + bhh[DD + cc];
    float bin = bih[2 * DD + cc];
    float bhn = bhh[2 * DD + cc];
    const float* whr = Whh + (size_t)(c0 + n15) * DD + q8;
    const float* whz = Whh + (size_t)(DD + c0 + n15) * DD + q8;

    for (int t = 0; t < TT; ++t) {
      f32x4 accr = {}, accz = {}, acchn = {}, accin = {};
      if (t > 0) {
        waitcnt_ge(&hcnt[t - 1], 64);  // h_{t-1} complete (all 1024 cols)
        const unsigned* aptr = h32[t & 1] + (size_t)rb * DD + q8;
#pragma unroll 4
        for (int kk = 0; kk < 32; ++kk) {
          bf16x8 a = ld8a(aptr + kk * 32);
          accr = MFMA16(a, ld8f(whr + kk * 32), accr);
          accz = MFMA16(a, ld8f(whz + kk * 32), accz);
          acchn = MFMA16(a, *(const bf16x8*)(wl + 12288 + ((size_t)kk * 64 + lane) * 8), acchn);
        }
        waitcnt_ge(&zcnt[t - 1], 16);  // z_{t-1} ready
        const unsigned* zptr = z32 + (size_t)rb * SS + q8;
#pragma unroll
        for (int kk = 0; kk < 8; ++kk) {
          bf16x8 a = ld8a(zptr + kk * 32);
          accr = MFMA16(a, *(const bf16x8*)(wl + ((size_t)(0 * 8 + kk) * 64 + lane) * 8), accr);
          accz = MFMA16(a, *(const bf16x8*)(wl + ((size_t)(1 * 8 + kk) * 64 + lane) * 8), accz);
          accin = MFMA16(a, *(const bf16x8*)(wl + ((size_t)(2 * 8 + kk) * 64 + lane) * 8), accin);
        }
      }
      unsigned* ho32 = h32[t & 1];
      unsigned* hn32 = h32[(t + 1) & 1];
      __bf16* hall_t = h_all + (size_t)t * BB * DD;
      int mb = wv * 16 + q4;
#pragma unroll
      for (int r = 0; r < 4; ++r) {
        int mm = mb + r;
        float rg = fsig(accr[r] + brs);
        float zg = fsig(accz[r] + bzs);
        float ng = ftanh(accin[r] + bin + rg * (acchn[r] + bhn));
        float ho = (t > 0) ? ld_coh(ho32 + mm * DD + cc) : 0.f;
        float hn = (1.f - zg) * ng + zg * ho;
        st_coh(hn32 + mm * DD + cc, hn);
        hall_t[(size_t)mm * DD + cc] = (__bf16)hn;  // archive: cached store
      }
      signal_inc(&hcnt[t]);
    }
  } else {
    int p = blk - 64, c2 = p * 16 + n15;
    float bmv = bm[c2], bvv = bv[c2];
    const float* wmh = Wm + (size_t)c2 * (II + DD) + II + q8;
    const float* wvh = Wv + (size_t)c2 * (II + DD) + II + q8;

    for (int t = 0; t < TT; ++t) {
      waitcnt_ge(&hcnt[t], 64);  // h_t ready
      f32x4 am = {}, av = {};
      const unsigned* hptr = h32[(t + 1) & 1] + (size_t)rb * DD + q8;
#pragma unroll 4
      for (int kk = 0; kk < 32; ++kk) {
        bf16x8 a = ld8a(hptr + kk * 32);
        am = MFMA16(a, ld8f(wmh + kk * 32), am);
        av = MFMA16(a, ld8f(wvh + kk * 32), av);
      }
      int mb = wv * 16 + q4;
#pragma unroll
      for (int r = 0; r < 4; ++r) {
        int mm = mb + r;
        size_t gidx = ((size_t)t * BB + mm) * SS + c2;
        float mean = am[r] + bmv + (float)xm[gidx];
        float vr = av[r] + bvv + (float)xv[gidx];
        float sd = __expf(0.5f * vr);
        float zt = noise[gidx] * sd + mean;
        st_coh(z32 + mm * SS + c2, zt);
        z_all[gidx] = (__bf16)zt;  // archive: cached store
      }
      signal_inc(&zcnt[t]);
    }
  }
}

// ---------------------------------------------------------------------------
// Decoder layer 0: elu([h_all | z_all] @ W0.T + b0) -> a0 (ws), K=1280
// ---------------------------------------------------------------------------
__global__ __launch_bounds__(256, 2) void k_dec0(const char* __restrict__ doutc,
                                                 const char* __restrict__ ws,
                                                 const float* __restrict__ W0,
                                                 const float* __restrict__ b0,
                                                 __bf16* __restrict__ C) {
  const __bf16* h_all = (const __bf16*)doutc;
  const __bf16* z_all = (const __bf16*)(ws + OFF_Z);
  int m0 = blockIdx.x * 128, n0 = blockIdx.y * 128;
  int tid = threadIdx.x, lane = tid & 63, w = tid >> 6;
  int wm = w >> 1, wn = w & 1;
  int n15 = lane & 15, q8 = (lane >> 4) * 8, q4 = (lane >> 4) * 4;

  const __bf16* hrow[4];
  const __bf16* zrow[4];
  const float* brow[4];
#pragma unroll
  for (int i = 0; i < 4; ++i) {
    int row = m0 + wm * 64 + i * 16 + n15;  // m = b*256 + t
    int b = row >> 8, tq = row & 255;
    hrow[i] = h_all + ((size_t)tq * BB + b) * DD + q8;
    zrow[i] = z_all + ((size_t)tq * BB + b) * SS + q8;
  }
#pragma unroll
  for (int j = 0; j < 4; ++j)
    brow[j] = W0 + (size_t)(n0 + wn * 64 + j * 16 + n15) * (DD + SS) + q8;

  f32x4 acc[4][4] = {};
  for (int k = 0; k < DD + SS; k += 32) {
    bf16x8 af[4], bfv[4];
#pragma unroll
    for (int i = 0; i < 4; ++i)
      af[i] = (k < DD) ? *(const bf16x8*)(hrow[i] + k) : *(const bf16x8*)(zrow[i] + k - DD);
#pragma unroll
    for (int j = 0; j < 4; ++j) bfv[j] = ld8f(brow[j] + k);
#pragma unroll
    for (int i = 0; i < 4; ++i)
#pragma unroll
      for (int j = 0; j < 4; ++j) acc[i][j] = MFMA16(af[i], bfv[j], acc[i][j]);
  }
#pragma unroll
  for (int i = 0; i < 4; ++i) {
    int mr = m0 + wm * 64 + i * 16 + q4;
#pragma unroll
    for (int j = 0; j < 4; ++j) {
      int c = n0 + wn * 64 + j * 16 + n15;
      float bb = b0[c];
#pragma unroll
      for (int r = 0; r < 4; ++r) {
        float v = acc[i][j][r] + bb;
        v = v > 0.f ? v : (__expf(v) - 1.f);
        C[(size_t)(mr + r) * HH + c] = (__bf16)v;
      }
    }
  }
}

// ---------------------------------------------------------------------------
// Decoder mid layer: C = elu(A @ W.T + b), K = N = 1024, contiguous bf16 A/C
// ---------------------------------------------------------------------------
__global__ __launch_bounds__(256, 2) void k_dec_mid(const __bf16* __restrict__ A,
                                                    const float* __restrict__ W,
                                                    const float* __restrict__ bias,
                                                    __bf16* __restrict__ C) {
  int m0 = blockIdx.x * 128, n0 = blockIdx.y * 128;
  int tid = threadIdx.x, lane = tid & 63, w = tid >> 6;
  int wm = w >> 1, wn = w & 1;
  int n15 = lane & 15, q8 = (lane >> 4) * 8, q4 = (lane >> 4) * 4;

  const __bf16* arow[4];
  const float* brow[4];
#pragma unroll
  for (int i = 0; i < 4; ++i) arow[i] = A + (size_t)(m0 + wm * 64 + i * 16 + n15) * DD + q8;
#pragma unroll
  for (int j = 0; j < 4; ++j) brow[j] = W + (size_t)(n0 + wn * 64 + j * 16 + n15) * DD + q8;

  f32x4 acc[4][4] = {};
  for (int k = 0; k < DD; k += 32) {
    bf16x8 af[4], bfv[4];
#pragma unroll
    for (int i = 0; i < 4; ++i) af[i] = *(const bf16x8*)(arow[i] + k);
#pragma unroll
    for (int j = 0; j < 4; ++j) bfv[j] = ld8f(brow[j] + k);
#pragma unroll
    for (int i = 0; i < 4; ++i)
#pragma unroll
      for (int j = 0; j < 4; ++j) acc[i][j] = MFMA16(af[i], bfv[j], acc[i][j]);
  }
#pragma unroll
  for (int i = 0; i < 4; ++i) {
    int mr = m0 + wm * 64 + i * 16 + q4;
#pragma unroll
    for (int j = 0; j < 4; ++j) {
      int c = n0 + wn * 64 + j * 16 + n15;
      float bb = bias[c];
#pragma unroll
      for (int r = 0; r < 4; ++r) {
        float v = acc[i][j][r] + bb;
        v = v > 0.f ? v : (__expf(v) - 1.f);
        C[(size_t)(mr + r) * HH + c] = (__bf16)v;
      }
    }
  }
}

// ---------------------------------------------------------------------------
// Decoder layer 3 + output assembly (fp32 outputs):
// outd[b,t,:] = d (t<255); outh[b,0,:] = x[b,0,:]; outh[b,t+1,:] = x[b,t,:]+d
// ---------------------------------------------------------------------------
__global__ __launch_bounds__(256, 2) void k_dec3(const __bf16* __restrict__ A,
                                                 const float* __restrict__ W3,
                                                 const float* __restrict__ b3,
                                                 const float* __restrict__ x,
                                                 float* __restrict__ outd,
                                                 float* __restrict__ outh) {
  int m0 = blockIdx.x * 128, n0 = blockIdx.y * 128;
  int tid = threadIdx.x, lane = tid & 63, w = tid >> 6;
  int wm = w >> 1, wn = w & 1;
  int n15 = lane & 15, q8 = (lane >> 4) * 8, q4 = (lane >> 4) * 4;

  const __bf16* arow[4];
  const float* brow[4];
#pragma unroll
  for (int i = 0; i < 4; ++i) arow[i] = A + (size_t)(m0 + wm * 64 + i * 16 + n15) * HH + q8;
#pragma unroll
  for (int j = 0; j < 4; ++j) brow[j] = W3 + (size_t)(n0 + wn * 64 + j * 16 + n15) * HH + q8;

  f32x4 acc[4][4] = {};
  for (int k = 0; k < HH; k += 32) {
    bf16x8 af[4], bfv[4];
#pragma unroll
    for (int i = 0; i < 4; ++i) af[i] = *(const bf16x8*)(arow[i] + k);
#pragma unroll
    for (int j = 0; j < 4; ++j) bfv[j] = ld8f(brow[j] + k);
#pragma unroll
    for (int i = 0; i < 4; ++i)
#pragma unroll
      for (int j = 0; j < 4; ++j) acc[i][j] = MFMA16(af[i], bfv[j], acc[i][j]);
  }
#pragma unroll
  for (int i = 0; i < 4; ++i) {
    int mr = m0 + wm * 64 + i * 16 + q4;
#pragma unroll
    for (int j = 0; j < 4; ++j) {
      int c = n0 + wn * 64 + j * 16 + n15;
      float b3v = b3[c];
#pragma unroll
      for (int r = 0; r < 4; ++r) {
        int mm = mr + r;
        int b = mm >> 8, tq = mm & 255;
        float dv = acc[i][j][r] + b3v;
        if (tq < 255) {
          outd[((size_t)b * 255 + tq) * II + c] = dv;
          outh[((size_t)b * TT + tq + 1) * II + c] = x[((size_t)b * TT + tq) * II + c] + dv;
        }
        if (tq == 0) outh[((size_t)b * TT) * II + c] = x[((size_t)b * TT) * II + c];
      }
    }
  }
}

// ---------------------------------------------------------------------------
extern "C" void kernel_launch(void* const* d_in, const int* in_sizes, int n_in,
                              void* d_out, int out_size, void* d_ws, size_t ws_size,
                              hipStream_t stream) {
  const float* x = (const float*)d_in[0];
  const float* noise = (const float*)d_in[1];
  const float* W_ih = (const float*)d_in[2];
  const float* W_hh = (const float*)d_in[3];
  const float* b_ih = (const float*)d_in[4];
  const float* b_hh = (const float*)d_in[5];
  const float* Wm = (const float*)d_in[6];
  const float* bm = (const float*)d_in[7];
  const float* Wv = (const float*)d_in[8];
  const float* bv = (const float*)d_in[9];
  const float* dW0 = (const float*)d_in[10];
  const float* db0 = (const float*)d_in[11];
  const float* dW1 = (const float*)d_in[12];
  const float* db1 = (const float*)d_in[13];
  const float* dW2 = (const float*)d_in[14];
  const float* db2 = (const float*)d_in[15];
  const float* dW3 = (const float*)d_in[16];
  const float* db3 = (const float*)d_in[17];

  char* ws = (char*)d_ws;
  char* doutc = (char*)d_out;
  __bf16* a0 = (__bf16*)(ws + OFF_A);  // dec0 out
  __bf16* a1 = (__bf16*)doutc;         // dec1 out (over dead h_all)
  __bf16* a2 = (__bf16*)(ws + OFF_A);  // dec2 out (over dead a0)

  // 1) x-dependent posterior halves (bf16, into d_out scratch) + zero counters
  k_xmv<<<dim3(256, 8), 256, 0, stream>>>(x, Wm, Wv, doutc, ws);

  // 2) persistent sequential scan (single launch, coherence-bypassing handoff)
  k_scan<<<80, 256, 0, stream>>>(W_ih, W_hh, b_ih, b_hh, Wm, bm, Wv, bv, noise, ws, doutc);

  // 3) decoder
  k_dec0<<<dim3(128, 8), 256, 0, stream>>>(doutc, ws, dW0, db0, a0);
  k_dec_mid<<<dim3(128, 8), 256, 0, stream>>>(a0, dW1, db1, a1);
  k_dec_mid<<<dim3(128, 8), 256, 0, stream>>>(a1, dW2, db2, a2);
  k_dec3<<<dim3(128, 4), 256, 0, stream>>>(a2, dW3, db3, x, (float*)doutc,
                                           (float*)doutc + OUTD_ELEMS);
}

// Round 7
// 5642.912 us; speedup vs baseline: 2.9262x; 2.9262x over previous
//
#include <hip/hip_runtime.h>
#include <hip/hip_bf16.h>
#include <string.h>

typedef __bf16 bf16x8 __attribute__((ext_vector_type(8)));
typedef float f32x4 __attribute__((ext_vector_type(4)));

#define MFMA16(a, b, c) __builtin_amdgcn_mfma_f32_16x16x32_bf16((a), (b), (c), 0, 0, 0)

#define BB 64
#define TT 256
#define II 512
#define SS 256
#define DD 1024
#define HH 1024

// ---- ws layout (bytes); total ~42.3 MB (<= 43.02 MB proven) ----------------
#define OFF_A ((size_t)0)           // 32MB bf16 activation slot (a0, then a2)
#define OFF_Z ((size_t)33554432)    // 8MB bf16 z archive (T,B,S)
#define OFF_HB ((size_t)41943040)   // bf16 [2][64][1024] h handoff (atomic 2B stores)
#define OFF_ZB ((size_t)42205184)   // bf16 [64][256] z handoff
#define OFF_CNT ((size_t)42237952)  // int hcnt[256] | zcnt[256]

// ---- d_out (fp32, 66,977,792 B) scratch layout -----------------------------
// [0,32MB): h_all bf16  (dead after dec0 -> a1 bf16)
// [34MB,42MB): xm bf16 (T,B,S)  [42MB,50MB): xv bf16 (T,B,S) (dead after scan)
#define DO_XM ((size_t)35651584)
#define DO_XV ((size_t)44040192)
#define OUTD_ELEMS 8355840  // 64*255*512

#define NGRU 128  // GRU blocks (8 h-cols each)
#define NPST 16   // posterior blocks (16 z-cols each)

__device__ __forceinline__ float fsig(float x) { return 1.f / (1.f + __expf(-x)); }
__device__ __forceinline__ float ftanh(float x) {
  float ax = __builtin_fabsf(x);
  float e = __expf(-2.f * ax);
  float r = (1.f - e) / (1.f + e);
  return __builtin_copysignf(r, x);
}

__device__ __forceinline__ bf16x8 ld8f(const float* p) {
  float4 a = *(const float4*)p;
  float4 b = *(const float4*)(p + 4);
  bf16x8 r;
  r[0] = (__bf16)a.x; r[1] = (__bf16)a.y; r[2] = (__bf16)a.z; r[3] = (__bf16)a.w;
  r[4] = (__bf16)b.x; r[5] = (__bf16)b.y; r[6] = (__bf16)b.z; r[7] = (__bf16)b.w;
  return r;
}

// ---- sync: relaxed poll + one acquire (L2 inv) / drain + relaxed signal ----
__device__ __forceinline__ void wait_acq(int* p, int target) {
  if (threadIdx.x == 0) {
    while (__hip_atomic_load(p, __ATOMIC_RELAXED, __HIP_MEMORY_SCOPE_AGENT) < target)
      __builtin_amdgcn_s_sleep(1);
    (void)__hip_atomic_load(p, __ATOMIC_ACQUIRE, __HIP_MEMORY_SCOPE_AGENT);  // one inv
  }
  __syncthreads();
}
__device__ __forceinline__ void signal(int* p) {
  asm volatile("s_waitcnt vmcnt(0)" ::: "memory");  // handoff stores at L3
  __syncthreads();
  if (threadIdx.x == 0)
    __hip_atomic_fetch_add(p, 1, __ATOMIC_RELAXED, __HIP_MEMORY_SCOPE_AGENT);
}
// 2-byte write-through (agent-relaxed) store of a bf16
__device__ __forceinline__ void st2(__bf16* p, float v) {
  __bf16 hv = (__bf16)v;
  unsigned short ub;
  __builtin_memcpy(&ub, &hv, 2);
  __hip_atomic_store((unsigned short*)p, ub, __ATOMIC_RELAXED, __HIP_MEMORY_SCOPE_AGENT);
}

// ---------------------------------------------------------------------------
// k_xmv: xm/xv = x @ Wm[:, :I].T, x @ Wv[:, :I].T -> bf16 into d_out scratch.
// Also zeroes the scan counters. m = t*64+b, n = 512, K = 512.  (proven r5/r6)
// ---------------------------------------------------------------------------
__global__ __launch_bounds__(256) void k_xmv(const float* __restrict__ x,
                                             const float* __restrict__ Wm,
                                             const float* __restrict__ Wv,
                                             char* __restrict__ doutc, char* __restrict__ ws) {
  if (blockIdx.x == 0 && blockIdx.y == 0) {
    int* cnt = (int*)(ws + OFF_CNT);
    cnt[threadIdx.x] = 0;
    cnt[threadIdx.x + 256] = 0;
  }
  __bf16* xm = (__bf16*)(doutc + DO_XM);
  __bf16* xv = (__bf16*)(doutc + DO_XV);

  int m0 = blockIdx.x * 64, n0 = blockIdx.y * 64;
  int tid = threadIdx.x, lane = tid & 63, wv = tid >> 6;
  int n15 = lane & 15, q8 = (lane >> 4) * 8;

  int row = m0 + wv * 16 + n15;  // m = t*64 + b
  int t = row >> 6, b = row & 63;
  const float* arow = x + ((size_t)(b * TT + t)) * II + q8;

  const float* brow[4];
#pragma unroll
  for (int j = 0; j < 4; ++j) {
    int c = n0 + j * 16 + n15;
    brow[j] = ((c < SS) ? (Wm + (size_t)c * (II + DD)) : (Wv + (size_t)(c - SS) * (II + DD))) + q8;
  }
  f32x4 acc[4] = {};
#pragma unroll 4
  for (int k = 0; k < II; k += 32) {
    bf16x8 a = ld8f(arow + k);
#pragma unroll
    for (int j = 0; j < 4; ++j) acc[j] = MFMA16(a, ld8f(brow[j] + k), acc[j]);
  }
  int mb = m0 + wv * 16 + (lane >> 4) * 4;
#pragma unroll
  for (int j = 0; j < 4; ++j) {
    int c = n0 + j * 16 + n15;
    __bf16* dst = (c < SS) ? (xm + c) : (xv + (c - SS));
#pragma unroll
    for (int r = 0; r < 4; ++r) dst[(size_t)(mb + r) * SS] = (__bf16)acc[j][r];
  }
}

// ---------------------------------------------------------------------------
// k_scan v3: persistent, all weights LDS-resident.
// Blocks 0..127: GRU, 8 h-cols each. LDS: W_hh all gates (48KB) + W_ih (12KB),
//   bank-swizzled. fp32 h carry in registers. Handoff h: bf16, 2B agent stores.
// Blocks 128..143: posterior, 16 z-cols each. LDS: Wm/Wv h-part (64KB).
// Per-step sync: relaxed poll -> one acquire; A-fragments batch-prefetched.
// ---------------------------------------------------------------------------
__global__ __launch_bounds__(256, 1) void k_scan(
    const float* __restrict__ Wih, const float* __restrict__ Whh,
    const float* __restrict__ bih, const float* __restrict__ bhh,
    const float* __restrict__ Wm, const float* __restrict__ bm,
    const float* __restrict__ Wv, const float* __restrict__ bv,
    const float* __restrict__ noise, char* __restrict__ ws, char* __restrict__ doutc) {
  __shared__ __bf16 smem[32768];  // 64 KB

  __bf16* hbL[2] = {(__bf16*)(ws + OFF_HB), (__bf16*)(ws + OFF_HB) + (size_t)BB * DD};
  __bf16* zb = (__bf16*)(ws + OFF_ZB);
  __bf16* z_all = (__bf16*)(ws + OFF_Z);
  __bf16* h_all = (__bf16*)doutc;
  const __bf16* xm = (const __bf16*)(doutc + DO_XM);
  const __bf16* xv = (const __bf16*)(doutc + DO_XV);
  int* hcnt = (int*)(ws + OFF_CNT);
  int* zcnt = hcnt + 256;

  int blk = blockIdx.x, tid = threadIdx.x, lane = tid & 63, wv = tid >> 6;
  int n15 = lane & 15, q = lane >> 4, q8 = q * 8, q4 = q * 4;
  const int rb = wv * 16 + n15;  // A-fragment batch row

  if (blk < NGRU) {
    int c0 = blk * 8;
    int col8 = n15 & 7;
    int swq = (q + ((col8 >> 1) & 3)) & 3;  // bank swizzle (<=2-way, free)
    // ---- stage W_hh (3 gates x 8 cols x K=1024) into LDS [0,24576) elts
    for (int u = tid; u < 3072; u += 256) {
      int qq = u & 3, col = (u >> 2) & 7, kk = (u >> 5) & 31, g = u >> 10;
      int sq = (qq + ((col >> 1) & 3)) & 3;
      *(bf16x8*)(smem + ((((g * 32 + kk) * 8 + col) * 4) + sq) * 8) =
          ld8f(Whh + ((size_t)(g * DD + c0 + col)) * DD + kk * 32 + qq * 8);
    }
    // ---- stage W_ih (3 gates x 8 cols x K=256) into LDS [24576,30720) elts
    for (int u = tid; u < 768; u += 256) {
      int qq = u & 3, col = (u >> 2) & 7, kk = (u >> 5) & 7, g = u >> 8;
      int sq = (qq + ((col >> 1) & 3)) & 3;
      *(bf16x8*)(smem + 24576 + ((((g * 8 + kk) * 8 + col) * 4) + sq) * 8) =
          ld8f(Wih + ((size_t)(g * DD + c0 + col)) * SS + kk * 32 + qq * 8);
    }
    __syncthreads();

    int ccb = c0 + col8;  // output col (lanes n15>=8 duplicate, never stored)
    float brs = bih[ccb] + bhh[ccb];
    float bzs = bih[DD + ccb] + bhh[DD + ccb];
    float bin = bih[2 * DD + ccb];
    float bhn = bhh[2 * DD + ccb];
    f32x4 hcarry = {};  // fp32 h for rows mb..mb+3, col ccb — registers!
    int mb = wv * 16 + q4;

    for (int t = 0; t < TT; ++t) {
      f32x4 accr = {}, accz = {}, acchn = {}, accin = {};
      if (t > 0) {
        wait_acq(&hcnt[t - 1], NGRU);
        // batch-prefetch h_{t-1} A-fragments (plain dwordx4 after inv)
        const __bf16* hp = hbL[t & 1] + (size_t)rb * DD + q8;
        bf16x8 hA[32];
#pragma unroll
        for (int kk = 0; kk < 32; ++kk) hA[kk] = *(const bf16x8*)(hp + kk * 32);
#pragma unroll
        for (int kk = 0; kk < 32; ++kk) {
          const __bf16* wb = smem + ((size_t)kk * 8 + col8) * 32 + swq * 8;
          accr = MFMA16(hA[kk], *(const bf16x8*)(wb), accr);
          accz = MFMA16(hA[kk], *(const bf16x8*)(wb + 8192), accz);
          acchn = MFMA16(hA[kk], *(const bf16x8*)(wb + 16384), acchn);
        }
        wait_acq(&zcnt[t - 1], NPST);
        const __bf16* zp = zb + (size_t)rb * SS + q8;
        bf16x8 zA[8];
#pragma unroll
        for (int kk = 0; kk < 8; ++kk) zA[kk] = *(const bf16x8*)(zp + kk * 32);
#pragma unroll
        for (int kk = 0; kk < 8; ++kk) {
          const __bf16* wb = smem + 24576 + ((size_t)kk * 8 + col8) * 32 + swq * 8;
          accr = MFMA16(zA[kk], *(const bf16x8*)(wb), accr);
          accz = MFMA16(zA[kk], *(const bf16x8*)(wb + 2048), accz);
          accin = MFMA16(zA[kk], *(const bf16x8*)(wb + 4096), accin);
        }
      }
      __bf16* hw = hbL[(t + 1) & 1];
      __bf16* hall_t = h_all + (size_t)t * BB * DD;
#pragma unroll
      for (int r = 0; r < 4; ++r) {
        int mm = mb + r;
        float rg = fsig(accr[r] + brs);
        float zg = fsig(accz[r] + bzs);
        float ng = ftanh(accin[r] + bin + rg * (acchn[r] + bhn));
        float hn = (1.f - zg) * ng + zg * hcarry[r];
        hcarry[r] = hn;
        if (n15 < 8) {
          st2(hw + (size_t)mm * DD + ccb, hn);          // handoff (write-through)
          hall_t[(size_t)mm * DD + ccb] = (__bf16)hn;   // archive (cached)
        }
      }
      signal(&hcnt[t]);
    }
  } else {
    int p = blk - NGRU, cp0 = p * 16;
    int swq = (q + ((n15 >> 1) & 3)) & 3;
    // ---- stage Wm/Wv h-part (2 x 16 cols x K=1024) into LDS (64 KB)
    for (int u = tid; u < 4096; u += 256) {
      int qq = u & 3, col = (u >> 2) & 15, kk = (u >> 6) & 31, mv = u >> 11;
      int sq = (qq + ((col >> 1) & 3)) & 3;
      const float* src = (mv ? Wv : Wm) + ((size_t)(cp0 + col)) * (II + DD) + II + kk * 32 + qq * 8;
      *(bf16x8*)(smem + ((((mv * 32 + kk) * 16 + col) * 4) + sq) * 8) = ld8f(src);
    }
    __syncthreads();

    int c2 = cp0 + n15;
    float bmv = bm[c2], bvv = bv[c2];
    int mb = wv * 16 + q4;

    for (int t = 0; t < TT; ++t) {
      wait_acq(&hcnt[t], NGRU);
      const __bf16* hp = hbL[(t + 1) & 1] + (size_t)rb * DD + q8;
      bf16x8 hA[32];
#pragma unroll
      for (int kk = 0; kk < 32; ++kk) hA[kk] = *(const bf16x8*)(hp + kk * 32);
      f32x4 am = {}, av = {};
#pragma unroll
      for (int kk = 0; kk < 32; ++kk) {
        const __bf16* wb = smem + ((size_t)kk * 16 + n15) * 32 + swq * 8;
        am = MFMA16(hA[kk], *(const bf16x8*)(wb), am);
        av = MFMA16(hA[kk], *(const bf16x8*)(wb + 16384), av);
      }
#pragma unroll
      for (int r = 0; r < 4; ++r) {
        int mm = mb + r;
        size_t gidx = ((size_t)t * BB + mm) * SS + c2;
        float mean = am[r] + bmv + (float)xm[gidx];
        float vr = av[r] + bvv + (float)xv[gidx];
        float sd = __expf(0.5f * vr);
        float zt = noise[gidx] * sd + mean;
        st2(zb + (size_t)mm * SS + c2, zt);  // handoff
        z_all[gidx] = (__bf16)zt;            // archive
      }
      signal(&zcnt[t]);
    }
  }
}

// ---------------------------------------------------------------------------
// Decoder layer 0: elu([h_all | z_all] @ W0.T + b0) -> a0 (ws), K=1280 (proven)
// ---------------------------------------------------------------------------
__global__ __launch_bounds__(256, 2) void k_dec0(const char* __restrict__ doutc,
                                                 const char* __restrict__ ws,
                                                 const float* __restrict__ W0,
                                                 const float* __restrict__ b0,
                                                 __bf16* __restrict__ C) {
  const __bf16* h_all = (const __bf16*)doutc;
  const __bf16* z_all = (const __bf16*)(ws + OFF_Z);
  int m0 = blockIdx.x * 128, n0 = blockIdx.y * 128;
  int tid = threadIdx.x, lane = tid & 63, w = tid >> 6;
  int wm = w >> 1, wn = w & 1;
  int n15 = lane & 15, q8 = (lane >> 4) * 8, q4 = (lane >> 4) * 4;

  const __bf16* hrow[4];
  const __bf16* zrow[4];
  const float* brow[4];
#pragma unroll
  for (int i = 0; i < 4; ++i) {
    int row = m0 + wm * 64 + i * 16 + n15;  // m = b*256 + t
    int b = row >> 8, tq = row & 255;
    hrow[i] = h_all + ((size_t)tq * BB + b) * DD + q8;
    zrow[i] = z_all + ((size_t)tq * BB + b) * SS + q8;
  }
#pragma unroll
  for (int j = 0; j < 4; ++j)
    brow[j] = W0 + (size_t)(n0 + wn * 64 + j * 16 + n15) * (DD + SS) + q8;

  f32x4 acc[4][4] = {};
  for (int k = 0; k < DD + SS; k += 32) {
    bf16x8 af[4], bfv[4];
#pragma unroll
    for (int i = 0; i < 4; ++i)
      af[i] = (k < DD) ? *(const bf16x8*)(hrow[i] + k) : *(const bf16x8*)(zrow[i] + k - DD);
#pragma unroll
    for (int j = 0; j < 4; ++j) bfv[j] = ld8f(brow[j] + k);
#pragma unroll
    for (int i = 0; i < 4; ++i)
#pragma unroll
      for (int j = 0; j < 4; ++j) acc[i][j] = MFMA16(af[i], bfv[j], acc[i][j]);
  }
#pragma unroll
  for (int i = 0; i < 4; ++i) {
    int mr = m0 + wm * 64 + i * 16 + q4;
#pragma unroll
    for (int j = 0; j < 4; ++j) {
      int c = n0 + wn * 64 + j * 16 + n15;
      float bb = b0[c];
#pragma unroll
      for (int r = 0; r < 4; ++r) {
        float v = acc[i][j][r] + bb;
        v = v > 0.f ? v : (__expf(v) - 1.f);
        C[(size_t)(mr + r) * HH + c] = (__bf16)v;
      }
    }
  }
}

// ---------------------------------------------------------------------------
// Decoder mid layer: C = elu(A @ W.T + b), K = N = 1024 (proven)
// ---------------------------------------------------------------------------
__global__ __launch_bounds__(256, 2) void k_dec_mid(const __bf16* __restrict__ A,
                                                    const float* __restrict__ W,
                                                    const float* __restrict__ bias,
                                                    __bf16* __restrict__ C) {
  int m0 = blockIdx.x * 128, n0 = blockIdx.y * 128;
  int tid = threadIdx.x, lane = tid & 63, w = tid >> 6;
  int wm = w >> 1, wn = w & 1;
  int n15 = lane & 15, q8 = (lane >> 4) * 8, q4 = (lane >> 4) * 4;

  const __bf16* arow[4];
  const float* brow[4];
#pragma unroll
  for (int i = 0; i < 4; ++i) arow[i] = A + (size_t)(m0 + wm * 64 + i * 16 + n15) * DD + q8;
#pragma unroll
  for (int j = 0; j < 4; ++j) brow[j] = W + (size_t)(n0 + wn * 64 + j * 16 + n15) * DD + q8;

  f32x4 acc[4][4] = {};
  for (int k = 0; k < DD; k += 32) {
    bf16x8 af[4], bfv[4];
#pragma unroll
    for (int i = 0; i < 4; ++i) af[i] = *(const bf16x8*)(arow[i] + k);
#pragma unroll
    for (int j = 0; j < 4; ++j) bfv[j] = ld8f(brow[j] + k);
#pragma unroll
    for (int i = 0; i < 4; ++i)
#pragma unroll
      for (int j = 0; j < 4; ++j) acc[i][j] = MFMA16(af[i], bfv[j], acc[i][j]);
  }
#pragma unroll
  for (int i = 0; i < 4; ++i) {
    int mr = m0 + wm * 64 + i * 16 + q4;
#pragma unroll
    for (int j = 0; j < 4; ++j) {
      int c = n0 + wn * 64 + j * 16 + n15;
      float bb = bias[c];
#pragma unroll
      for (int r = 0; r < 4; ++r) {
        float v = acc[i][j][r] + bb;
        v = v > 0.f ? v : (__expf(v) - 1.f);
        C[(size_t)(mr + r) * HH + c] = (__bf16)v;
      }
    }
  }
}

// ---------------------------------------------------------------------------
// Decoder layer 3 + output assembly (fp32 outputs) (proven)
// ---------------------------------------------------------------------------
__global__ __launch_bounds__(256, 2) void k_dec3(const __bf16* __restrict__ A,
                                                 const float* __restrict__ W3,
                                                 const float* __restrict__ b3,
                                                 const float* __restrict__ x,
                                                 float* __restrict__ outd,
                                                 float* __restrict__ outh) {
  int m0 = blockIdx.x * 128, n0 = blockIdx.y * 128;
  int tid = threadIdx.x, lane = tid & 63, w = tid >> 6;
  int wm = w >> 1, wn = w & 1;
  int n15 = lane & 15, q8 = (lane >> 4) * 8, q4 = (lane >> 4) * 4;

  const __bf16* arow[4];
  const float* brow[4];
#pragma unroll
  for (int i = 0; i < 4; ++i) arow[i] = A + (size_t)(m0 + wm * 64 + i * 16 + n15) * HH + q8;
#pragma unroll
  for (int j = 0; j < 4; ++j) brow[j] = W3 + (size_t)(n0 + wn * 64 + j * 16 + n15) * HH + q8;

  f32x4 acc[4][4] = {};
  for (int k = 0; k < HH; k += 32) {
    bf16x8 af[4], bfv[4];
#pragma unroll
    for (int i = 0; i < 4; ++i) af[i] = *(const bf16x8*)(arow[i] + k);
#pragma unroll
    for (int j = 0; j < 4; ++j) bfv[j] = ld8f(brow[j] + k);
#pragma unroll
    for (int i = 0; i < 4; ++i)
#pragma unroll
      for (int j = 0; j < 4; ++j) acc[i][j] = MFMA16(af[i], bfv[j], acc[i][j]);
  }
#pragma unroll
  for (int i = 0; i < 4; ++i) {
    int mr = m0 + wm * 64 + i * 16 + q4;
#pragma unroll
    for (int j = 0; j < 4; ++j) {
      int c = n0 + wn * 64 + j * 16 + n15;
      float b3v = b3[c];
#pragma unroll
      for (int r = 0; r < 4; ++r) {
        int mm = mr + r;
        int b = mm >> 8, tq = mm & 255;
        float dv = acc[i][j][r] + b3v;
        if (tq < 255) {
          outd[((size_t)b * 255 + tq) * II + c] = dv;
          outh[((size_t)b * TT + tq + 1) * II + c] = x[((size_t)b * TT + tq) * II + c] + dv;
        }
        if (tq == 0) outh[((size_t)b * TT) * II + c] = x[((size_t)b * TT) * II + c];
      }
    }
  }
}

// ---------------------------------------------------------------------------
extern "C" void kernel_launch(void* const* d_in, const int* in_sizes, int n_in,
                              void* d_out, int out_size, void* d_ws, size_t ws_size,
                              hipStream_t stream) {
  const float* x = (const float*)d_in[0];
  const float* noise = (const float*)d_in[1];
  const float* W_ih = (const float*)d_in[2];
  const float* W_hh = (const float*)d_in[3];
  const float* b_ih = (const float*)d_in[4];
  const float* b_hh = (const float*)d_in[5];
  const float* Wm = (const float*)d_in[6];
  const float* bm = (const float*)d_in[7];
  const float* Wv = (const float*)d_in[8];
  const float* bv = (const float*)d_in[9];
  const float* dW0 = (const float*)d_in[10];
  const float* db0 = (const float*)d_in[11];
  const float* dW1 = (const float*)d_in[12];
  const float* db1 = (const float*)d_in[13];
  const float* dW2 = (const float*)d_in[14];
  const float* db2 = (const float*)d_in[15];
  const float* dW3 = (const float*)d_in[16];
  const float* db3 = (const float*)d_in[17];

  char* ws = (char*)d_ws;
  char* doutc = (char*)d_out;
  __bf16* a0 = (__bf16*)(ws + OFF_A);  // dec0 out
  __bf16* a1 = (__bf16*)doutc;         // dec1 out (over dead h_all)
  __bf16* a2 = (__bf16*)(ws + OFF_A);  // dec2 out (over dead a0)

  // 1) x-dependent posterior halves (bf16, into d_out scratch) + zero counters
  k_xmv<<<dim3(256, 8), 256, 0, stream>>>(x, Wm, Wv, doutc, ws);

  // 2) persistent scan: 128 GRU + 16 posterior blocks, all weights in LDS
  k_scan<<<NGRU + NPST, 256, 0, stream>>>(W_ih, W_hh, b_ih, b_hh, Wm, bm, Wv, bv, noise, ws,
                                          doutc);

  // 3) decoder
  k_dec0<<<dim3(128, 8), 256, 0, stream>>>(doutc, ws, dW0, db0, a0);
  k_dec_mid<<<dim3(128, 8), 256, 0, stream>>>(a0, dW1, db1, a1);
  k_dec_mid<<<dim3(128, 8), 256, 0, stream>>>(a1, dW2, db2, a2);
  k_dec3<<<dim3(128, 4), 256, 0, stream>>>(a2, dW3, db3, x, (float*)doutc,
                                           (float*)doutc + OUTD_ELEMS);
}